// Round 5
// baseline (348.998 us; speedup 1.0000x reference)
//
#include <hip/hip_runtime.h>

// RNN_arch_2: 16-step RNN, B=16384, D_IN=64, D_H=256, D_MID=64, D_OUT=4.
// R5: R4 had 1 resident block/CU (AGPR+VGPR ~160/wave at 8-wave blocks) and
// LDS-bound A-frag redundancy (32-col strips: 1 read per 2 MFMA). Back to
// 4-wave/256-thr blocks with 64-col strips (1 read per 4 MFMA), grid 512 ->
// 2 truly independent blocks/CU to overlap barriers/tanh with MFMA.
// Fusions: mid-GEMM shares pre-GEMM A-frags (same h buffer, same region);
// fc done as MFMA with zero-padded Wf (kills the scalar-FMA loop).
// Single barrier per region; h/x/mid parity double-buffered.

typedef _Float16 half8 __attribute__((ext_vector_type(8)));
typedef float floatx4 __attribute__((ext_vector_type(4)));

#define T_STEPS  16
#define BATCH    16384
#define BLK_ROWS 32
#define HS       264   // h_lds row stride (f16)
#define XS       72    // x_lds row stride (f16)
#define MS       72    // mid_lds row stride (f16)

// ws layout (f16): Wi[256x64], Wh[256x256], Wo[64x256], Wf_pad[16x64] (rows 4..15 zero)
#define WS_WI 0
#define WS_WH 16384
#define WS_WO 81920
#define WS_WF 98304
#define WS_TOT 99328

__global__ void prep_kernel(const float* __restrict__ Wi, const float* __restrict__ Wh,
                            const float* __restrict__ Wo, const float* __restrict__ Wf,
                            _Float16* __restrict__ ws) {
    int i = blockIdx.x * 256 + threadIdx.x;
    if (i >= WS_TOT) return;
    float v;
    if (i < WS_WH)           v = Wi[i];
    else if (i < WS_WO)      v = Wh[i - WS_WH];
    else if (i < WS_WF)      v = Wo[i - WS_WO];
    else if (i < WS_WF + 256) v = Wf[i - WS_WF];
    else                     v = 0.0f;   // Wf pad rows 4..15
    ws[i] = (_Float16)v;
}

__device__ inline float fast_tanh(float x) {
    float t = __builtin_amdgcn_exp2f(x * 2.8853900817779268f);
    return 1.0f - 2.0f * __builtin_amdgcn_rcpf(t + 1.0f);
}

__device__ inline half8 cvt8pair(float4 a, float4 b) {
    half8 h;
    h[0] = (_Float16)a.x; h[1] = (_Float16)a.y; h[2] = (_Float16)a.z; h[3] = (_Float16)a.w;
    h[4] = (_Float16)b.x; h[5] = (_Float16)b.y; h[6] = (_Float16)b.z; h[7] = (_Float16)b.w;
    return h;
}

#define MFMA(a, b, c) __builtin_amdgcn_mfma_f32_16x16x32_f16((a), (b), (c), 0, 0, 0)

__global__ __launch_bounds__(256, 2) void rnn_kernel(
    const float* __restrict__ x,    const float* __restrict__ hc1,
    const _Float16* __restrict__ wf16,
    const float* __restrict__ bi,   const float* __restrict__ bh,
    const float* __restrict__ bo,   const float* __restrict__ bfc,
    float* __restrict__ out)
{
    __shared__ _Float16 h_lds[2][BLK_ROWS * HS];
    __shared__ _Float16 xf[2][BLK_ROWS * XS];
    __shared__ _Float16 midb[2][BLK_ROWS * MS];

    const int tid  = threadIdx.x;
    const int w    = tid >> 6;        // wave 0..3 -> 64-col pre strip / 16-col mid strip
    const int lane = tid & 63;
    const int l16  = lane & 15;
    const int quad = lane >> 4;
    const int b0   = blockIdx.x * BLK_ROWS;

    // biases in registers
    float bpre[4];
    #pragma unroll
    for (int nt = 0; nt < 4; ++nt) {
        int c = w * 64 + nt * 16 + l16;
        bpre[nt] = bi[c] + bh[c];
    }
    const int midc = w * 16 + l16;
    float bo_r  = bo[midc];
    float bfc_r = bfc[l16 & 3];

    // persistent pre-GEMM B fragments: n=l16 (+16*nt +64*w), k=quad*8+j
    half8 wcat[10][4];
    #pragma unroll
    for (int ks = 0; ks < 10; ++ks) {
        #pragma unroll
        for (int nt = 0; nt < 4; ++nt) {
            int j = w * 64 + nt * 16 + l16;
            wcat[ks][nt] = (ks < 2)
                ? *(const half8*)(wf16 + WS_WI + (size_t)j * 64  + ks * 32 + quad * 8)
                : *(const half8*)(wf16 + WS_WH + (size_t)j * 256 + (ks - 2) * 32 + quad * 8);
        }
    }

    // stage hc1 -> h_lds[0]: 256 thr, 32 cols each
    {
        int rr = tid >> 3, c0 = (tid & 7) * 32;
        const float4* s = (const float4*)&hc1[(size_t)(b0 + rr) * 256 + c0];
        float4 a = s[0], b = s[1], c = s[2], d = s[3];
        float4 e = s[4], f = s[5], g = s[6], hh = s[7];
        *(half8*)&h_lds[0][rr * HS + c0]      = cvt8pair(a, b);
        *(half8*)&h_lds[0][rr * HS + c0 + 8]  = cvt8pair(c, d);
        *(half8*)&h_lds[0][rr * HS + c0 + 16] = cvt8pair(e, f);
        *(half8*)&h_lds[0][rr * HS + c0 + 24] = cvt8pair(g, hh);
    }
    // stage x(0) -> xf[0]: 256 thr, 8 cols each
    {
        int rr = tid >> 3, c0 = (tid & 7) * 8;
        const float4* s = (const float4*)&x[(size_t)(b0 + rr) * 64 + c0];
        *(half8*)&xf[0][rr * XS + c0] = cvt8pair(s[0], s[1]);
    }

    __syncthreads();

    // region r: preGEMM(h_{r+1}) + mid(out_{r-1}) fused on same A-frags;
    // fc(out_{r-2}) as MFMA on wave 3; x(r+1) prefetch. One barrier/region.
    for (int r = 0; r < T_STEPS + 2; ++r) {
        const int cur = r & 1, nxt = cur ^ 1;

        if (r < T_STEPS) {
            // x(r+1) prefetch (issued early, consumed at region end)
            float4 xa, xb;
            const int xr = tid >> 3, xc = (tid & 7) * 8;
            if (r < T_STEPS - 1) {
                const float* xp = x + ((size_t)(r + 1) * BATCH + b0 + xr) * 64 + xc;
                xa = ((const float4*)xp)[0];
                xb = ((const float4*)xp)[1];
            }

            #pragma unroll
            for (int mt = 0; mt < 2; ++mt) {
                floatx4 a0 = {0.f,0.f,0.f,0.f}, a1 = {0.f,0.f,0.f,0.f};
                floatx4 a2 = {0.f,0.f,0.f,0.f}, a3 = {0.f,0.f,0.f,0.f};
                floatx4 am = {0.f,0.f,0.f,0.f};
                const int arow = mt * 16 + l16;
                #pragma unroll
                for (int hv = 0; hv < 2; ++hv) {
                    half8 wo4[4];
                    #pragma unroll
                    for (int i = 0; i < 4; ++i)
                        wo4[i] = *(const half8*)(wf16 + WS_WO + (size_t)midc * 256 + (hv * 4 + i) * 32 + quad * 8);
                    #pragma unroll
                    for (int i = 0; i < 4; ++i) {
                        const int ks = hv * 4 + i;
                        half8 af = *(const half8*)&h_lds[cur][arow * HS + ks * 32 + quad * 8];
                        a0 = MFMA(af, wcat[2 + ks][0], a0);
                        a1 = MFMA(af, wcat[2 + ks][1], a1);
                        a2 = MFMA(af, wcat[2 + ks][2], a2);
                        a3 = MFMA(af, wcat[2 + ks][3], a3);
                        am = MFMA(af, wo4[i], am);
                    }
                }
                #pragma unroll
                for (int ks = 0; ks < 2; ++ks) {
                    half8 af = *(const half8*)&xf[cur][arow * XS + ks * 32 + quad * 8];
                    a0 = MFMA(af, wcat[ks][0], a0);
                    a1 = MFMA(af, wcat[ks][1], a1);
                    a2 = MFMA(af, wcat[ks][2], a2);
                    a3 = MFMA(af, wcat[ks][3], a3);
                }
                // h_{r+1} epilogue
                #pragma unroll
                for (int rr = 0; rr < 4; ++rr) {
                    int row = mt * 16 + quad * 4 + rr;
                    _Float16* hd = &h_lds[nxt][row * HS + w * 64 + l16];
                    hd[0]  = (_Float16)fast_tanh(a0[rr] + bpre[0]);
                    hd[16] = (_Float16)fast_tanh(a1[rr] + bpre[1]);
                    hd[32] = (_Float16)fast_tanh(a2[rr] + bpre[2]);
                    hd[48] = (_Float16)fast_tanh(a3[rr] + bpre[3]);
                    if (r >= 1)
                        midb[cur][row * MS + midc] = (_Float16)fast_tanh(am[rr] + bo_r);
                }
            }

            if (r < T_STEPS - 1) {
                half8 hx = cvt8pair(xa, xb);
                *(half8*)&xf[nxt][xr * XS + xc] = hx;
            }
        } else if (r == T_STEPS) {
            // standalone mid for out_{15}: reads h_16 in h_lds[cur]
            #pragma unroll
            for (int mt = 0; mt < 2; ++mt) {
                floatx4 am = {0.f,0.f,0.f,0.f};
                const int arow = mt * 16 + l16;
                #pragma unroll
                for (int hv = 0; hv < 2; ++hv) {
                    half8 wo4[4];
                    #pragma unroll
                    for (int i = 0; i < 4; ++i)
                        wo4[i] = *(const half8*)(wf16 + WS_WO + (size_t)midc * 256 + (hv * 4 + i) * 32 + quad * 8);
                    #pragma unroll
                    for (int i = 0; i < 4; ++i) {
                        half8 af = *(const half8*)&h_lds[cur][arow * HS + (hv * 4 + i) * 32 + quad * 8];
                        am = MFMA(af, wo4[i], am);
                    }
                }
                #pragma unroll
                for (int rr = 0; rr < 4; ++rr) {
                    int row = mt * 16 + quad * 4 + rr;
                    midb[cur][row * MS + midc] = (_Float16)fast_tanh(am[rr] + bo_r);
                }
            }
        }

        // fc(out_{r-2}) via MFMA on wave 3; reads midb[nxt] (written region r-1)
        if (r >= 2 && w == 3) {
            half8 wb0 = *(const half8*)(wf16 + WS_WF + (size_t)l16 * 64 + quad * 8);
            half8 wb1 = *(const half8*)(wf16 + WS_WF + (size_t)l16 * 64 + 32 + quad * 8);
            #pragma unroll
            for (int mt = 0; mt < 2; ++mt) {
                floatx4 ac = {0.f,0.f,0.f,0.f};
                half8 af0 = *(const half8*)&midb[nxt][(mt * 16 + l16) * MS + quad * 8];
                half8 af1 = *(const half8*)&midb[nxt][(mt * 16 + l16) * MS + 32 + quad * 8];
                ac = MFMA(af0, wb0, ac);
                ac = MFMA(af1, wb1, ac);
                if (l16 < 4) {
                    #pragma unroll
                    for (int rr = 0; rr < 4; ++rr) {
                        int row = mt * 16 + quad * 4 + rr;
                        out[((size_t)(r - 2) * BATCH + b0 + row) * 4 + l16] = ac[rr] + bfc_r;
                    }
                }
            }
        }

        __syncthreads();
    }

    // h_final (fp32): h_16 lives in h_lds[0] (written at region 15, nxt=0)
    {
        int rr = tid >> 3, c0 = (tid & 7) * 32;
        float4* dst = (float4*)&out[(size_t)T_STEPS * BATCH * 4 + (size_t)(b0 + rr) * 256 + c0];
        #pragma unroll
        for (int p = 0; p < 4; ++p) {
            half8 v = *(const half8*)&h_lds[0][rr * HS + c0 + p * 8];
            float4 o0, o1;
            o0.x = (float)v[0]; o0.y = (float)v[1]; o0.z = (float)v[2]; o0.w = (float)v[3];
            o1.x = (float)v[4]; o1.y = (float)v[5]; o1.z = (float)v[6]; o1.w = (float)v[7];
            dst[p * 2]     = o0;
            dst[p * 2 + 1] = o1;
        }
    }
}

extern "C" void kernel_launch(void* const* d_in, const int* in_sizes, int n_in,
                              void* d_out, int out_size, void* d_ws, size_t ws_size,
                              hipStream_t stream) {
    const float* x   = (const float*)d_in[0];
    const float* hc1 = (const float*)d_in[1];
    const float* Wi  = (const float*)d_in[2];
    const float* bi  = (const float*)d_in[3];
    const float* Wh  = (const float*)d_in[4];
    const float* bh  = (const float*)d_in[5];
    const float* Wo  = (const float*)d_in[6];
    const float* bo  = (const float*)d_in[7];
    const float* Wf  = (const float*)d_in[8];
    const float* bf  = (const float*)d_in[9];
    _Float16* ws = (_Float16*)d_ws;

    prep_kernel<<<(WS_TOT + 255) / 256, 256, 0, stream>>>(Wi, Wh, Wo, Wf, ws);
    rnn_kernel<<<BATCH / BLK_ROWS, 256, 0, stream>>>(
        x, hc1, ws, bi, bh, bo, bf, (float*)d_out);
}